// Round 2
// baseline (221.439 us; speedup 1.0000x reference)
//
#include <hip/hip_runtime.h>
#include <math.h>

#define NQ 10
#define NL 4

// ---------- cross-lane primitives (VALU where possible) ----------
__device__ __forceinline__ float rfl(float x) {
  return __int_as_float(__builtin_amdgcn_readfirstlane(__float_as_int(x)));
}
template<int CTRL>
__device__ __forceinline__ float dppx(float v) {  // quad_perm DPP (VALU pipe)
  return __int_as_float(__builtin_amdgcn_update_dpp(0, __float_as_int(v), CTRL, 0xF, 0xF, true));
}
template<int OFF>
__device__ __forceinline__ float swzx(float v) {  // ds_swizzle (LDS pipe, no addr VGPR)
  return __int_as_float(__builtin_amdgcn_ds_swizzle(__float_as_int(v), OFF));
}
__device__ __forceinline__ void pl16swap(float &a, float &b) {
  asm("v_permlane16_swap_b32 %0, %1" : "+v"(a), "+v"(b));
}
__device__ __forceinline__ void pl32swap(float &a, float &b) {
  asm("v_permlane32_swap_b32 %0, %1" : "+v"(a), "+v"(b));
}

// partner fetch for lane-bit LB in {0,1,2,3}: xor 1,2 via DPP quad_perm; xor 4,8 via ds_swizzle
template<int LB>
__device__ __forceinline__ float lpart(float v) {
  if constexpr (LB == 0) return dppx<0xB1>(v);        // quad_perm [1,0,3,2] = xor1
  else if constexpr (LB == 1) return dppx<0x4E>(v);   // quad_perm [2,3,0,1] = xor2
  else if constexpr (LB == 2) return swzx<0x101F>(v); // BitMode xor4
  else return swzx<0x201F>(v);                        // BitMode xor8
}

// ---------- gates ----------
// 1q gate on a register-bit qubit (pure VALU; coefficients are SGPRs)
template<int RB>
__device__ __forceinline__ void gate_rbit(float ar[16], float ai[16],
    float u00r, float u00i, float u01r, float u01i,
    float u10r, float u10i, float u11r, float u11i) {
#pragma unroll
  for (int r0 = 0; r0 < 16; ++r0) {
    if ((r0 >> RB) & 1) continue;
    const int r1 = r0 | (1 << RB);
    const float a0r = ar[r0], a0i = ai[r0];
    const float a1r = ar[r1], a1i = ai[r1];
    ar[r0] = u00r * a0r - u00i * a0i + u01r * a1r - u01i * a1i;
    ai[r0] = u00r * a0i + u00i * a0r + u01r * a1i + u01i * a1r;
    ar[r1] = u10r * a0r - u10i * a0i + u11r * a1r - u11i * a1i;
    ai[r1] = u10r * a0i + u10i * a0r + u11r * a1i + u11i * a1r;
  }
}

// 1q gate on lane-bit LB in {0..3}: partner via DPP/swizzle, own value kept.
// cS = (hi ? u11 : u00), cP = (hi ? u10 : u01) selected by caller.
template<int LB>
__device__ __forceinline__ void gate_lbit_p(float ar[16], float ai[16],
    float cSr, float cSi, float cPr, float cPi) {
#pragma unroll
  for (int r = 0; r < 16; ++r) {
    const float pr = lpart<LB>(ar[r]);
    const float pi = lpart<LB>(ai[r]);
    const float sr = ar[r], si = ai[r];
    ar[r] = cSr * sr - cSi * si + cPr * pr - cPi * pi;
    ai[r] = cSr * si + cSi * sr + cPr * pi + cPi * pr;
  }
}

// 1q gate on lane-bit 4 (xor16, IS32=false) or 5 (xor32, IS32=true) via permlane*_swap:
// after swap, lo holds the bit=0 data in all lanes, hi the bit=1 data.
// cL = (hi ? u10 : u00), cH = (hi ? u11 : u01) selected by caller.
template<bool IS32>
__device__ __forceinline__ void gate_lbit_swap(float ar[16], float ai[16],
    float cLr, float cLi, float cHr, float cHi) {
#pragma unroll
  for (int r = 0; r < 16; ++r) {
    float lr = ar[r], hr = ar[r];
    float li = ai[r], hi_ = ai[r];
    if constexpr (IS32) { pl32swap(lr, hr); pl32swap(li, hi_); }
    else                { pl16swap(lr, hr); pl16swap(li, hi_); }
    ar[r] = cLr * lr - cLi * li + cHr * hr - cHi * hi_;
    ai[r] = cLr * li + cLi * lr + cHr * hi_ + cHi * hr;
  }
}

// ---------- whole CNOT ring as ONE linear permutation ----------
// dst[r'][lane'] = src[gray4(r') ^ ((lane'&1)*12)][(lane'^(lane'>>1)) ^ ((r'&1)<<5)]
// B[g] = bpermute(addr_{parity(g)}, a[g]); dst[r'] = lane-odd ? B[gray^12] : B[gray]
__device__ __forceinline__ void ring_comp(float a[16], int addr0, int addr1, bool odd) {
  float B[16];
#pragma unroll
  for (int g = 0; g < 16; ++g) {
    const int par = ((g ^ (g >> 1) ^ (g >> 2) ^ (g >> 3)) & 1);
    B[g] = __int_as_float(__builtin_amdgcn_ds_bpermute(par ? addr1 : addr0,
                                                       __float_as_int(a[g])));
  }
#pragma unroll
  for (int r = 0; r < 16; ++r) {
    const int g = (r ^ (r >> 1));
    a[r] = odd ? B[g ^ 12] : B[g];
  }
}

// full 64-lane sum, cheap pipes for every stage
__device__ __forceinline__ float wave_sum(float v) {
  v += dppx<0xB1>(v);
  v += dppx<0x4E>(v);
  v += swzx<0x101F>(v);
  v += swzx<0x201F>(v);
  { float a = v, b = v; pl16swap(a, b); v = a + b; }
  { float a = v, b = v; pl32swap(a, b); v = a + b; }
  return v;
}

__global__ __launch_bounds__(256) void qsim_kernel(const float* __restrict__ x,
                                                   const float* __restrict__ w,
                                                   float* __restrict__ out,
                                                   int batch) {
  // ---- per-block: the 40 shared Rot matrices into LDS
  __shared__ float gsh[NL * NQ * 8];
  const int tid = threadIdx.x;
  if (tid < NL * NQ) {
    const float phi = w[tid * 3 + 0];
    const float th  = w[tid * 3 + 1];
    const float om  = w[tid * 3 + 2];
    float c, s, cp, sp, cm, sm;
    sincosf(0.5f * th, &s, &c);
    sincosf(-0.5f * (phi + om), &sp, &cp);
    sincosf(0.5f * (phi - om), &sm, &cm);
    float* g = &gsh[tid * 8];
    g[0] = cp * c;  g[1] = sp * c;
    g[2] = -cm * s; g[3] = -sm * s;
    g[4] = cm * s;  g[5] = -sm * s;
    g[6] = cp * c;  g[7] = -sp * c;
  }
  __syncthreads();

  const int samp = (int)(blockIdx.x * (blockDim.x >> 6)) + (tid >> 6);
  const int lane = tid & 63;
  if (samp >= batch) return;

  // ring-permutation bpermute addresses (byte): L = lane ^ (lane>>1)
  const int addr0 = 4 * (lane ^ (lane >> 1));
  const int addr1 = addr0 ^ 128;
  const bool lodd = (lane & 1);

  // ---- encoding: product state built directly
  const float* xb = x + samp * NQ;
  float cq[NQ], sq[NQ];
#pragma unroll
  for (int q = 0; q < NQ; ++q) sincosf(0.5f * xb[q], &sq[q], &cq[q]);

  float lfac = ((lane >> 0) & 1 ? sq[9] : cq[9]);
  lfac *= ((lane >> 1) & 1 ? sq[8] : cq[8]);
  lfac *= ((lane >> 2) & 1 ? sq[7] : cq[7]);
  lfac *= ((lane >> 3) & 1 ? sq[6] : cq[6]);
  lfac *= ((lane >> 4) & 1 ? sq[5] : cq[5]);
  lfac *= ((lane >> 5) & 1 ? sq[4] : cq[4]);

  float ar[16], ai[16];
#pragma unroll
  for (int r = 0; r < 16; ++r) {
    float f = lfac;
    f *= ((r >> 0) & 1 ? sq[3] : cq[3]);
    f *= ((r >> 1) & 1 ? sq[2] : cq[2]);
    f *= ((r >> 2) & 1 ? sq[1] : cq[1]);
    f *= ((r >> 3) & 1 ? sq[0] : cq[0]);
    ar[r] = f;
    ai[r] = 0.f;
  }

  // ---- layers
#pragma unroll
  for (int l = 0; l < NL; ++l) {
    const float* gl = &gsh[l * NQ * 8];

    // qubits 0..3: register-bit gates, SGPR coefficients
#pragma unroll
    for (int q = 0; q < 4; ++q) {
      const float* g = gl + q * 8;
      const float u00r = rfl(g[0]), u00i = rfl(g[1]);
      const float u01r = rfl(g[2]), u01i = rfl(g[3]);
      const float u10r = rfl(g[4]), u10i = rfl(g[5]);
      const float u11r = rfl(g[6]), u11i = rfl(g[7]);
      if (q == 0)      gate_rbit<3>(ar, ai, u00r,u00i,u01r,u01i,u10r,u10i,u11r,u11i);
      else if (q == 1) gate_rbit<2>(ar, ai, u00r,u00i,u01r,u01i,u10r,u10i,u11r,u11i);
      else if (q == 2) gate_rbit<1>(ar, ai, u00r,u00i,u01r,u01i,u10r,u10i,u11r,u11i);
      else             gate_rbit<0>(ar, ai, u00r,u00i,u01r,u01i,u10r,u10i,u11r,u11i);
    }
    // qubit 4 (lane bit 5, xor32): permlane32_swap
    {
      const float* g = gl + 4 * 8;
      const bool hb = (lane >> 5) & 1;
      const float cLr = hb ? rfl(g[4]) : rfl(g[0]);
      const float cLi = hb ? rfl(g[5]) : rfl(g[1]);
      const float cHr = hb ? rfl(g[6]) : rfl(g[2]);
      const float cHi = hb ? rfl(g[7]) : rfl(g[3]);
      gate_lbit_swap<true>(ar, ai, cLr, cLi, cHr, cHi);
    }
    // qubit 5 (lane bit 4, xor16): permlane16_swap
    {
      const float* g = gl + 5 * 8;
      const bool hb = (lane >> 4) & 1;
      const float cLr = hb ? rfl(g[4]) : rfl(g[0]);
      const float cLi = hb ? rfl(g[5]) : rfl(g[1]);
      const float cHr = hb ? rfl(g[6]) : rfl(g[2]);
      const float cHi = hb ? rfl(g[7]) : rfl(g[3]);
      gate_lbit_swap<false>(ar, ai, cLr, cLi, cHr, cHi);
    }
    // qubits 6..9 (lane bits 3..0): partner gates (ds_swizzle / DPP)
#pragma unroll
    for (int q = 6; q < 10; ++q) {
      const float* g = gl + q * 8;
      const bool hb = (lane >> (9 - q)) & 1;
      const float cSr = hb ? rfl(g[6]) : rfl(g[0]);
      const float cSi = hb ? rfl(g[7]) : rfl(g[1]);
      const float cPr = hb ? rfl(g[4]) : rfl(g[2]);
      const float cPi = hb ? rfl(g[5]) : rfl(g[3]);
      if (q == 6)      gate_lbit_p<3>(ar, ai, cSr, cSi, cPr, cPi);
      else if (q == 7) gate_lbit_p<2>(ar, ai, cSr, cSi, cPr, cPi);
      else if (q == 8) gate_lbit_p<1>(ar, ai, cSr, cSi, cPr, cPi);
      else             gate_lbit_p<0>(ar, ai, cSr, cSi, cPr, cPi);
    }

    // entire CNOT ring as one permutation
    ring_comp(ar, addr0, addr1, lodd);
    ring_comp(ai, addr0, addr1, lodd);
  }

  // ---- measurement
  float p[16];
#pragma unroll
  for (int r = 0; r < 16; ++r) p[r] = ar[r] * ar[r] + ai[r] * ai[r];

  float z[NQ];
#pragma unroll
  for (int q = 0; q < 4; ++q) {
    const int rb = 3 - q;
    float acc = 0.f;
#pragma unroll
    for (int r = 0; r < 16; ++r) acc += ((r >> rb) & 1) ? -p[r] : p[r];
    z[q] = acc;
  }
  float P = 0.f;
#pragma unroll
  for (int r = 0; r < 16; ++r) P += p[r];
#pragma unroll
  for (int q = 4; q < NQ; ++q) {
    const int lb = 9 - q;
    z[q] = ((lane >> lb) & 1) ? -P : P;
  }

#pragma unroll
  for (int q = 0; q < NQ; ++q) z[q] = wave_sum(z[q]);

  if (lane == 0) {
#pragma unroll
    for (int q = 0; q < NQ; ++q) out[samp * NQ + q] = z[q];
  }
}

extern "C" void kernel_launch(void* const* d_in, const int* in_sizes, int n_in,
                              void* d_out, int out_size, void* d_ws, size_t ws_size,
                              hipStream_t stream) {
  const float* x = (const float*)d_in[0];
  const float* w = (const float*)d_in[1];
  float* out = (float*)d_out;
  const int batch = in_sizes[0] / NQ;
  const int waves_per_block = 256 / 64;
  const int grid = (batch + waves_per_block - 1) / waves_per_block;
  hipLaunchKernelGGL(qsim_kernel, dim3(grid), dim3(256), 0, stream, x, w, out, batch);
}